// Round 9
// baseline (627.335 us; speedup 1.0000x reference)
//
#include <hip/hip_runtime.h>
#include <hip/hip_bf16.h>
#include <hip/hip_fp8.h>
#include <math.h>

#define N_NODES 100000
#define N_EDGES 800000
#define SCAN_BLOCKS 98  // ceil(100000/1024)

typedef __attribute__((ext_vector_type(8))) short short8;
typedef __attribute__((ext_vector_type(4))) float f32x4;
typedef __attribute__((ext_vector_type(2))) float f32x2;

__device__ __forceinline__ unsigned short f2b(float f) {
    __hip_bfloat16 h = __float2bfloat16(f);
    return *reinterpret_cast<unsigned short*>(&h);
}
__device__ __forceinline__ float2 up2(unsigned u) {
    unsigned lo = u << 16;
    unsigned hi = u & 0xffff0000u;
    float2 r;
    __builtin_memcpy(&r.x, &lo, 4);
    __builtin_memcpy(&r.y, &hi, 4);
    return r;
}
// fp32 -> fp8 e4m3 (RNE, saturating)
__device__ __forceinline__ unsigned char f2fp8(float f) {
#if __has_builtin(__builtin_amdgcn_cvt_pk_fp8_f32)
    unsigned u = __builtin_amdgcn_cvt_pk_fp8_f32(f, f, 0u, false);
    return (unsigned char)(u & 0xffu);
#else
    __hip_fp8_e4m3 h(f);
    return (unsigned char)h.__x;
#endif
}
// 4-ch dot: fp8-e4m3-packed k (4 bytes) against pre-scaled q
__device__ __forceinline__ float dotk(float2 qa, float2 qb, unsigned k4) {
#if __has_builtin(__builtin_amdgcn_cvt_pk_f32_fp8)
    f32x2 lo = __builtin_amdgcn_cvt_pk_f32_fp8(k4, false);
    f32x2 hi = __builtin_amdgcn_cvt_pk_f32_fp8(k4, true);
    float p = lo[0] * qa.x;
    p = fmaf(lo[1], qa.y, p);
    p = fmaf(hi[0], qb.x, p);
    p = fmaf(hi[1], qb.y, p);
    return p;
#else
    __hip_fp8_e4m3 a, b, c, d;
    a.__x = (unsigned char)k4;
    b.__x = (unsigned char)(k4 >> 8);
    c.__x = (unsigned char)(k4 >> 16);
    d.__x = (unsigned char)(k4 >> 24);
    float p = (float)a * qa.x;
    p = fmaf((float)b, qa.y, p);
    p = fmaf((float)c, qb.x, p);
    p = fmaf((float)d, qb.y, p);
    return p;
#endif
}
// fp8x4 -> 4 floats (v dequant)
__device__ __forceinline__ f32x4 up4f8(unsigned v) {
    f32x4 r;
#if __has_builtin(__builtin_amdgcn_cvt_pk_f32_fp8)
    f32x2 lo = __builtin_amdgcn_cvt_pk_f32_fp8(v, false);
    f32x2 hi = __builtin_amdgcn_cvt_pk_f32_fp8(v, true);
    r[0] = lo[0]; r[1] = lo[1]; r[2] = hi[0]; r[3] = hi[1];
#else
    __hip_fp8_e4m3 a, b, c, d;
    a.__x = (unsigned char)v;
    b.__x = (unsigned char)(v >> 8);
    c.__x = (unsigned char)(v >> 16);
    d.__x = (unsigned char)(v >> 24);
    r[0] = (float)a; r[1] = (float)b; r[2] = (float)c; r[3] = (float)d;
#endif
    return r;
}
// 4-ch bf16 dot against pre-scaled q
__device__ __forceinline__ float dot4(float2 qa, float2 qb, unsigned k0, unsigned k1) {
    float2 x = up2(k0), y = up2(k1);
    float p = x.x * qa.x;
    p = fmaf(x.y, qa.y, p);
    p = fmaf(y.x, qb.x, p);
    p = fmaf(y.y, qb.y, p);
    return p;
}
// edge-index load; UNI: whole wave owns one node -> index is wave-uniform,
// force it scalar so gather addressing moves to the SALU pipe (r16).
template <bool UNI>
__device__ __forceinline__ int ldi(const int* __restrict__ p, int e) {
    int v = p[e];
    if constexpr (UNI) v = __builtin_amdgcn_readfirstlane(v);
    return v;
}

// ---------------- CSR build (dst-sorted adjacency) ----------------

__global__ void hist_kernel(const int* __restrict__ dst, int* __restrict__ deg) {
    int e = blockIdx.x * blockDim.x + threadIdx.x;
    if (e < N_EDGES) atomicAdd(&deg[dst[e]], 1);
}

__global__ __launch_bounds__(1024) void scan_part(const int* __restrict__ deg,
                                                  int* __restrict__ rowptr,
                                                  int* __restrict__ partials) {
    __shared__ int buf[1024];
    const int t = threadIdx.x;
    const int i = blockIdx.x * 1024 + t;
    int x = (i < N_NODES) ? deg[i] : 0;
    buf[t] = x;
    __syncthreads();
    for (int off = 1; off < 1024; off <<= 1) {
        int y = (t >= off) ? buf[t - off] : 0;
        __syncthreads();
        buf[t] += y;
        __syncthreads();
    }
    if (i < N_NODES) rowptr[i] = buf[t] - x;
    if (t == 1023) partials[blockIdx.x] = buf[t];
}

__global__ __launch_bounds__(128) void scan_tail(int* __restrict__ partials,
                                                 int* __restrict__ rowptr) {
    __shared__ int buf[128];
    const int t = threadIdx.x;
    int x = (t < SCAN_BLOCKS) ? partials[t] : 0;
    buf[t] = x;
    __syncthreads();
    for (int off = 1; off < 128; off <<= 1) {
        int y = (t >= off) ? buf[t - off] : 0;
        __syncthreads();
        buf[t] += y;
        __syncthreads();
    }
    if (t < SCAN_BLOCKS) partials[t] = buf[t] - x;
    if (t == 127) rowptr[N_NODES] = buf[127];
}

__global__ __launch_bounds__(1024) void scan_add(int* __restrict__ rowptr,
                                                 const int* __restrict__ partials) {
    const int i = blockIdx.x * 1024 + threadIdx.x;
    if (i < N_NODES) rowptr[i] += partials[blockIdx.x];
}

__global__ void scatter_kernel(const int* __restrict__ src, const int* __restrict__ dst,
                               const int* __restrict__ rowptr, int* __restrict__ cursor,
                               int* __restrict__ sorted_src) {
    int e = blockIdx.x * blockDim.x + threadIdx.x;
    if (e < N_EDGES) {
        int d = dst[e];
        int pos = atomicAdd(&cursor[d], 1);
        sorted_src[rowptr[d] + pos] = src[e];
    }
}

__global__ void fill_kernel(float* __restrict__ out, int n, float val) {
    int i = blockIdx.x * blockDim.x + threadIdx.x;
    if (i < n) out[i] = val;
}

// ---------------- helpers ----------------

__global__ void convert_kernel(const float* __restrict__ X, unsigned short* __restrict__ Y, int n4) {
    int i = blockIdx.x * blockDim.x + threadIdx.x;
    if (i < n4) {
        float4 f = ((const float4*)X)[i];
        ushort4 u;
        u.x = f2b(f.x); u.y = f2b(f.y); u.z = f2b(f.z); u.w = f2b(f.w);
        ((ushort4*)Y)[i] = u;
    }
}

// WT[4*HC][K] bf16. mode 0 (layers 2,3): row order [q | v | k | s].
// mode 1 (layer 1): [q | kv-interleaved | s] (per head 2C rows, groups of 8
// = {k[g*4..+3], v[g*4..+3]} so the gather reads one contiguous chunk per lane).
// biasF[4*HC] fp32 in the same row order.
__global__ void build_wt(const float* __restrict__ Wq, const float* __restrict__ Wk,
                         const float* __restrict__ Wv, const float* __restrict__ Wsk,
                         const float* __restrict__ bq, const float* __restrict__ bk,
                         const float* __restrict__ bv, const float* __restrict__ bsk,
                         unsigned short* __restrict__ WT, float* __restrict__ biasF,
                         int K, int HC, int C, int mode) {
    int total = 4 * HC * K;
    int idx = blockIdx.x * blockDim.x + threadIdx.x;
    if (idx >= total) return;
    int rowc = idx / K;
    int kk = idx - rowc * K;
    const float* W;
    const float* Bp;
    int cw;
    if (mode == 0) {
        if (rowc < HC)          { W = Wq;  Bp = bq;  cw = rowc; }
        else if (rowc < 2 * HC) { W = Wv;  Bp = bv;  cw = rowc - HC; }
        else if (rowc < 3 * HC) { W = Wk;  Bp = bk;  cw = rowc - 2 * HC; }
        else                    { W = Wsk; Bp = bsk; cw = rowc - 3 * HC; }
    } else {
        if (rowc < HC) {
            W = Wq; Bp = bq; cw = rowc;
        } else if (rowc < 3 * HC) {
            int u = rowc - HC;
            int h = u / (2 * C);
            int rr = u - h * 2 * C;
            int grp = rr >> 3, w = rr & 7;
            if (w < 4) { W = Wk; Bp = bk; cw = h * C + grp * 4 + w; }
            else       { W = Wv; Bp = bv; cw = h * C + grp * 4 + w - 4; }
        } else {
            W = Wsk; Bp = bsk; cw = rowc - 3 * HC;
        }
    }
    WT[idx] = f2b(W[(size_t)kk * HC + cw]);
    if (kk == 0) biasF[rowc] = Bp[cw];
}

// ---------------- MFMA bf16 GEMM ----------------
// r7: X-refetch across col-tiles is L3-absorbed — never trade occupancy for
// fetch. r9: union-LDS epilogue. r10: 2-range col->WT-row map (split/rq/rkv).
// r11: YMODE 2 fp8-e4m3 epilogue. r13: fp8 kv only in layer 1.
// r14: XCD-pinned X-stationary block remap (+8 us measured).
// YMODE: 0 = f32 out (ostride in floats), 1 = bf16 (shorts), 2 = fp8 (bytes).

template <int K, int YMODE>
__global__ __launch_bounds__(256) void mfma_gemm(
    const unsigned short* __restrict__ Xb, const unsigned short* __restrict__ WT,
    const float* __restrict__ biasF, void* __restrict__ Y,
    int ncols, int ostride, int split, int rq, int rkv) {
    constexpr int STR = 40;
    constexpr int ESTR = 136;  // bf16 epilogue row stride (shorts)
    __shared__ __align__(16) char smem[128 * ESTR * 2];  // 34816 B union
    unsigned short* Xs = (unsigned short*)smem;                  // 128*40 shorts
    unsigned short* Ws = (unsigned short*)(smem + 128 * STR * 2);
    const int t = threadIdx.x;
    const int wave = t >> 6, lane = t & 63, quad = lane >> 4, l16 = lane & 15;

    // XCD-pinned remap (r14)
    const int bid = blockIdx.x + blockIdx.y * gridDim.x;  // linear dispatch id
    const int nwg = gridDim.x * gridDim.y;
    const int nyt = gridDim.y;
    const int xcd = bid & 7;
    const int jj = bid >> 3;
    const int qq = nwg >> 3, rr = nwg & 7;
    const int base = xcd * qq + (xcd < rr ? xcd : rr);
    const int work = base + jj;
    const int xt = work / nyt;
    const int yt = work - xt * nyt;
    const int n0 = xt * 128, c0 = yt * 128;

    f32x4 acc[2][8];
#pragma unroll
    for (int i = 0; i < 2; ++i)
#pragma unroll
        for (int j = 0; j < 8; ++j)
#pragma unroll
            for (int r = 0; r < 4; ++r) acc[i][j][r] = 0.f;

    for (int k0 = 0; k0 < K; k0 += 32) {
#pragma unroll
        for (int i = 0; i < 2; ++i) {
            int idx = t + i * 256;
            int row = idx >> 2;
            int seg = (idx & 3) << 3;
            int gr = n0 + row;
            short8 xv;
#pragma unroll
            for (int z = 0; z < 8; ++z) xv[z] = 0;
            if (gr < N_NODES)
                xv = *(const short8*)(Xb + (size_t)gr * K + k0 + seg);
            *(short8*)(&Xs[row * STR + seg]) = xv;

            int c = c0 + row;
            short8 wv;
#pragma unroll
            for (int z = 0; z < 8; ++z) wv[z] = 0;
            if (c < ncols) {
                int wtrow = (c < split) ? (rq + c) : (rkv + (c - split));
                wv = *(const short8*)(WT + (size_t)wtrow * K + k0 + seg);
            }
            *(short8*)(&Ws[row * STR + seg]) = wv;
        }
        __syncthreads();

        short8 af0 = *(short8*)(&Xs[(wave * 32 + l16) * STR + quad * 8]);
        short8 af1 = *(short8*)(&Xs[(wave * 32 + 16 + l16) * STR + quad * 8]);
#pragma unroll
        for (int ct = 0; ct < 8; ++ct) {
            short8 bfr = *(short8*)(&Ws[(ct * 16 + l16) * STR + quad * 8]);
            acc[0][ct] = __builtin_amdgcn_mfma_f32_16x16x32_bf16(af0, bfr, acc[0][ct], 0, 0, 0);
            acc[1][ct] = __builtin_amdgcn_mfma_f32_16x16x32_bf16(af1, bfr, acc[1][ct], 0, 0, 0);
        }
        __syncthreads();  // also guards the epilogue's staging-LDS reuse
    }

    if constexpr (YMODE == 1) {
        unsigned short* Es = (unsigned short*)smem;  // 128 x ESTR, unioned
#pragma unroll
        for (int ct = 0; ct < 8; ++ct) {
            if (c0 + ct * 16 >= ncols) break;  // ncols % 32 == 0
            int col = c0 + ct * 16 + l16;
            int brow = (col < split) ? (rq + col) : (rkv + (col - split));
            float bv = biasF[brow];
#pragma unroll
            for (int rt = 0; rt < 2; ++rt)
#pragma unroll
                for (int r = 0; r < 4; ++r) {
                    int row = wave * 32 + rt * 16 + quad * 4 + r;
                    Es[row * ESTR + ct * 16 + l16] = f2b(acc[rt][ct][r] + bv);
                }
        }
        __syncthreads();
        const int erow = t >> 1;
        const int cb = (t & 1) * 8;
        const int gr = n0 + erow;
#pragma unroll
        for (int j = 0; j < 8; ++j) {
            int gc = c0 + j * 16 + cb;
            if (gr < N_NODES && gc < ncols)
                *(short8*)((unsigned short*)Y + (size_t)gr * ostride + gc) =
                    *(const short8*)(&Es[erow * ESTR + j * 16 + cb]);
        }
    } else if constexpr (YMODE == 2) {
        constexpr int EB = 144;  // byte stride, 16B-aligned
        unsigned char* Es = (unsigned char*)smem;  // 128 x EB bytes, unioned
#pragma unroll
        for (int ct = 0; ct < 8; ++ct) {
            if (c0 + ct * 16 >= ncols) break;  // ncols % 16 == 0
            int col = c0 + ct * 16 + l16;
            int brow = (col < split) ? (rq + col) : (rkv + (col - split));
            float bv = biasF[brow];
#pragma unroll
            for (int rt = 0; rt < 2; ++rt)
#pragma unroll
                for (int r = 0; r < 4; ++r) {
                    int row = wave * 32 + rt * 16 + quad * 4 + r;
                    Es[row * EB + ct * 16 + l16] = f2fp8(acc[rt][ct][r] + bv);
                }
        }
        __syncthreads();
        const int erow = t >> 1;
        const int q8 = (t & 1) * 64;
        const int gr = n0 + erow;
#pragma unroll
        for (int j = 0; j < 4; ++j) {
            int gc = c0 + q8 + j * 16;
            if (gr < N_NODES && gc < ncols)
                *(uint4*)((unsigned char*)Y + (size_t)gr * ostride + gc) =
                    *(const uint4*)(&Es[erow * EB + q8 + j * 16]);
        }
    } else {
#pragma unroll
        for (int ct = 0; ct < 8; ++ct) {
            int col = c0 + ct * 16 + l16;
            if (col >= ncols) continue;
            int brow = (col < split) ? (rq + col) : (rkv + (col - split));
            float bv = biasF[brow];
#pragma unroll
            for (int rt = 0; rt < 2; ++rt) {
#pragma unroll
                for (int r = 0; r < 4; ++r) {
                    int row = n0 + wave * 32 + rt * 16 + quad * 4 + r;
                    if (row < N_NODES)
                        ((float*)Y)[(size_t)row * ostride + col] = acc[rt][ct][r] + bv;
                }
            }
        }
    }
}

template <int K, int YMODE>
static inline void launch_gemm(const unsigned short* Xb, const unsigned short* WT,
                               const float* biasF, void* Y, int ncols, int ostride,
                               int split, int rq, int rkv, hipStream_t s) {
    const int GX = (N_NODES + 127) / 128;
    int ny = (ncols + 127) / 128;
    mfma_gemm<K, YMODE><<<dim3(GX, ny), 256, 0, s>>>(
        Xb, WT, biasF, Y, ncols, ostride, split, rq, rkv);
}

// ---------------- attention v7r2: per-layer kv precision, 4 ch/lane ---------
// KVM 0 (unused now, kept): F row [q | kv-int bf16 | ...], one 16B gather/lane.
// KVM 1 (layer 1): F row = q only (gC shorts); KV8 row = 2*gC bytes e4m3,
//   per head groups of 8 {k4|v4}: ONE uint2 (8B) gather per lane per edge.
// KVM 2 (layers 2,3): F row [q|v] bf16 (2*gC shorts); K8 row = gC bytes e4m3 k:
//   4B k + 8B v per lane per edge (v stays bf16 for accuracy).
// r16: when NPW==1 (NH=7 L1) the edge index is wave-uniform -> readfirstlane.
// r17: layer 3 switches to KVM 2 (k fp8) — 256->192 B/edge, logit-noise only.
// Logits tiny -> plain exp softmax is exact fp32. Dest holds skip; add (+ReLU).

template <int C, int NH, bool RELU, bool YBF, int KVM>
__global__ __launch_bounds__(256) void attn3(
    const unsigned short* __restrict__ F, const unsigned char* __restrict__ K8,
    const int* __restrict__ rowptr, const int* __restrict__ ssrc,
    void* __restrict__ Hv, int h0, int ostride) {
    constexpr int LPN = NH * C / 4;  // lanes per node
    constexpr int NPW = 64 / LPN;    // nodes per wave
    constexpr bool UNI = (NPW == 1); // wave-uniform edge indices
    constexpr int gC = NH * C;
    constexpr int Ms = (KVM == 1) ? gC : (KVM == 2) ? (2 * gC) : (3 * gC);
    constexpr int Mk = 2 * gC;       // KVM1 KV8 row stride (bytes)
    const int lane = threadIdx.x & 63;
    const int wave = (blockIdx.x * 256 + threadIdx.x) >> 6;
    const int slot = lane / LPN;
    const int cl = lane - slot * LPN;
    const int n = wave * NPW + slot;
    if (slot >= NPW || n >= N_NODES) return;  // no barriers below

    const int head = cl / (C / 4);
    const int c4 = (cl - head * (C / 4)) * 4;
    const int qoff = head * C + c4;
    const int voff = gC + qoff;                    // KVM2 v section (shorts)
    const int kv8off = 2 * (head * C + c4);        // KVM1 bytes {k4|v4}
    const int kvoff = gC + head * 2 * C + 2 * c4;  // KVM0 shorts interleaved
    const float SCALE2 = ((C == 64) ? 0.125f : 0.17677669529663687f) * 1.44269504f;

    uint2 qu = *(const uint2*)(F + (size_t)n * Ms + qoff);
    float2 qa = up2(qu.x), qb = up2(qu.y);
    qa.x *= SCALE2; qa.y *= SCALE2; qb.x *= SCALE2; qb.y *= SCALE2;
    int s0 = rowptr[n], s1 = rowptr[n + 1];
    if constexpr (UNI) {
        s0 = __builtin_amdgcn_readfirstlane(s0);
        s1 = __builtin_amdgcn_readfirstlane(s1);
    }

    float l = 0.f, a0 = 0.f, a1 = 0.f, a2 = 0.f, a3 = 0.f;
    int ei = s0;
    if constexpr (KVM == 1) {
        for (; ei + 3 < s1; ei += 4) {
            int iA = ldi<UNI>(ssrc, ei), iB = ldi<UNI>(ssrc, ei + 1);
            int iC = ldi<UNI>(ssrc, ei + 2), iD = ldi<UNI>(ssrc, ei + 3);
            uint2 A = *(const uint2*)(K8 + (size_t)iA * Mk + kv8off);
            uint2 B = *(const uint2*)(K8 + (size_t)iB * Mk + kv8off);
            uint2 Cu = *(const uint2*)(K8 + (size_t)iC * Mk + kv8off);
            uint2 D = *(const uint2*)(K8 + (size_t)iD * Mk + kv8off);
            float pA = dotk(qa, qb, A.x);
            float pB = dotk(qa, qb, B.x);
            float pC = dotk(qa, qb, Cu.x);
            float pD = dotk(qa, qb, D.x);
#pragma unroll
            for (int off = C / 8; off > 0; off >>= 1) {
                pA += __shfl_xor(pA, off);
                pB += __shfl_xor(pB, off);
                pC += __shfl_xor(pC, off);
                pD += __shfl_xor(pD, off);
            }
            float eA = exp2f(pA), eB = exp2f(pB), eC = exp2f(pC), eD = exp2f(pD);
            l += (eA + eB) + (eC + eD);
            f32x4 vA = up4f8(A.y), vB = up4f8(B.y), vC = up4f8(Cu.y), vD = up4f8(D.y);
            a0 = fmaf(eA, vA[0], fmaf(eB, vB[0], fmaf(eC, vC[0], fmaf(eD, vD[0], a0))));
            a1 = fmaf(eA, vA[1], fmaf(eB, vB[1], fmaf(eC, vC[1], fmaf(eD, vD[1], a1))));
            a2 = fmaf(eA, vA[2], fmaf(eB, vB[2], fmaf(eC, vC[2], fmaf(eD, vD[2], a2))));
            a3 = fmaf(eA, vA[3], fmaf(eB, vB[3], fmaf(eC, vC[3], fmaf(eD, vD[3], a3))));
        }
        if (ei + 1 < s1) {
            int iA = ldi<UNI>(ssrc, ei), iB = ldi<UNI>(ssrc, ei + 1);
            ei += 2;
            uint2 A = *(const uint2*)(K8 + (size_t)iA * Mk + kv8off);
            uint2 B = *(const uint2*)(K8 + (size_t)iB * Mk + kv8off);
            float pA = dotk(qa, qb, A.x);
            float pB = dotk(qa, qb, B.x);
#pragma unroll
            for (int off = C / 8; off > 0; off >>= 1) {
                pA += __shfl_xor(pA, off);
                pB += __shfl_xor(pB, off);
            }
            float eA = exp2f(pA), eB = exp2f(pB);
            l += eA + eB;
            f32x4 vA = up4f8(A.y), vB = up4f8(B.y);
            a0 = fmaf(eA, vA[0], fmaf(eB, vB[0], a0));
            a1 = fmaf(eA, vA[1], fmaf(eB, vB[1], a1));
            a2 = fmaf(eA, vA[2], fmaf(eB, vB[2], a2));
            a3 = fmaf(eA, vA[3], fmaf(eB, vB[3], a3));
        }
        if (ei < s1) {
            int iA = ldi<UNI>(ssrc, ei);
            uint2 A = *(const uint2*)(K8 + (size_t)iA * Mk + kv8off);
            float pA = dotk(qa, qb, A.x);
#pragma unroll
            for (int off = C / 8; off > 0; off >>= 1) pA += __shfl_xor(pA, off);
            float eA = exp2f(pA);
            l += eA;
            f32x4 vA = up4f8(A.y);
            a0 = fmaf(eA, vA[0], a0);
            a1 = fmaf(eA, vA[1], a1);
            a2 = fmaf(eA, vA[2], a2);
            a3 = fmaf(eA, vA[3], a3);
        }
    } else if constexpr (KVM == 2) {
        for (; ei + 3 < s1; ei += 4) {
            int iA = ldi<UNI>(ssrc, ei), iB = ldi<UNI>(ssrc, ei + 1);
            int iC = ldi<UNI>(ssrc, ei + 2), iD = ldi<UNI>(ssrc, ei + 3);
            unsigned kA = *(const unsigned*)(K8 + (size_t)iA * gC + qoff);
            unsigned kB = *(const unsigned*)(K8 + (size_t)iB * gC + qoff);
            unsigned kC = *(const unsigned*)(K8 + (size_t)iC * gC + qoff);
            unsigned kD = *(const unsigned*)(K8 + (size_t)iD * gC + qoff);
            uint2 vAu = *(const uint2*)(F + (size_t)iA * Ms + voff);
            uint2 vBu = *(const uint2*)(F + (size_t)iB * Ms + voff);
            uint2 vCu = *(const uint2*)(F + (size_t)iC * Ms + voff);
            uint2 vDu = *(const uint2*)(F + (size_t)iD * Ms + voff);
            float pA = dotk(qa, qb, kA);
            float pB = dotk(qa, qb, kB);
            float pC = dotk(qa, qb, kC);
            float pD = dotk(qa, qb, kD);
#pragma unroll
            for (int off = C / 8; off > 0; off >>= 1) {
                pA += __shfl_xor(pA, off);
                pB += __shfl_xor(pB, off);
                pC += __shfl_xor(pC, off);
                pD += __shfl_xor(pD, off);
            }
            float eA = exp2f(pA), eB = exp2f(pB), eC = exp2f(pC), eD = exp2f(pD);
            l += (eA + eB) + (eC + eD);
            float2 vA0 = up2(vAu.x), vA1 = up2(vAu.y);
            float2 vB0 = up2(vBu.x), vB1 = up2(vBu.y);
            float2 vC0 = up2(vCu.x), vC1 = up2(vCu.y);
            float2 vD0 = up2(vDu.x), vD1 = up2(vDu.y);
            a0 = fmaf(eA, vA0.x, fmaf(eB, vB0.x, fmaf(eC, vC0.x, fmaf(eD, vD0.x, a0))));
            a1 = fmaf(eA, vA0.y, fmaf(eB, vB0.y, fmaf(eC, vC0.y, fmaf(eD, vD0.y, a1))));
            a2 = fmaf(eA, vA1.x, fmaf(eB, vB1.x, fmaf(eC, vC1.x, fmaf(eD, vD1.x, a2))));
            a3 = fmaf(eA, vA1.y, fmaf(eB, vB1.y, fmaf(eC, vC1.y, fmaf(eD, vD1.y, a3))));
        }
        if (ei + 1 < s1) {
            int iA = ldi<UNI>(ssrc, ei), iB = ldi<UNI>(ssrc, ei + 1);
            ei += 2;
            unsigned kA = *(const unsigned*)(K8 + (size_t)iA * gC + qoff);
            unsigned kB = *(const unsigned*)(K8 + (size_t)iB * gC + qoff);
            uint2 vAu = *(const uint2*)(F + (size_t)iA * Ms + voff);
            uint2 vBu = *(const uint2*)(F + (size_t)iB * Ms + voff);
            float pA = dotk(qa, qb, kA);
            float pB = dotk(qa, qb, kB);
#pragma unroll
            for (int off = C / 8; off > 0; off >>= 1) {
                pA += __shfl_xor(pA, off);
                pB += __shfl_xor(pB, off);
            }
            float eA = exp2f(pA), eB = exp2f(pB);
            l += eA + eB;
            float2 vA0 = up2(vAu.x), vA1 = up2(vAu.y);
            float2 vB0 = up2(vBu.x), vB1 = up2(vBu.y);
            a0 = fmaf(eA, vA0.x, fmaf(eB, vB0.x, a0));
            a1 = fmaf(eA, vA0.y, fmaf(eB, vB0.y, a1));
            a2 = fmaf(eA, vA1.x, fmaf(eB, vB1.x, a2));
            a3 = fmaf(eA, vA1.y, fmaf(eB, vB1.y, a3));
        }
        if (ei < s1) {
            int iA = ldi<UNI>(ssrc, ei);
            unsigned kA = *(const unsigned*)(K8 + (size_t)iA * gC + qoff);
            uint2 vAu = *(const uint2*)(F + (size_t)iA * Ms + voff);
            float pA = dotk(qa, qb, kA);
#pragma unroll
            for (int off = C / 8; off > 0; off >>= 1) pA += __shfl_xor(pA, off);
            float eA = exp2f(pA);
            l += eA;
            float2 vA0 = up2(vAu.x), vA1 = up2(vAu.y);
            a0 = fmaf(eA, vA0.x, a0);
            a1 = fmaf(eA, vA0.y, a1);
            a2 = fmaf(eA, vA1.x, a2);
            a3 = fmaf(eA, vA1.y, a3);
        }
    } else {
        for (; ei + 3 < s1; ei += 4) {
            int iA = ldi<UNI>(ssrc, ei), iB = ldi<UNI>(ssrc, ei + 1);
            int iC = ldi<UNI>(ssrc, ei + 2), iD = ldi<UNI>(ssrc, ei + 3);
            uint4 A = *(const uint4*)(F + (size_t)iA * Ms + kvoff);
            uint4 B = *(const uint4*)(F + (size_t)iB * Ms + kvoff);
            uint4 Cv = *(const uint4*)(F + (size_t)iC * Ms + kvoff);
            uint4 D = *(const uint4*)(F + (size_t)iD * Ms + kvoff);
            float pA = dot4(qa, qb, A.x, A.y);
            float pB = dot4(qa, qb, B.x, B.y);
            float pC = dot4(qa, qb, Cv.x, Cv.y);
            float pD = dot4(qa, qb, D.x, D.y);
#pragma unroll
            for (int off = C / 8; off > 0; off >>= 1) {
                pA += __shfl_xor(pA, off);
                pB += __shfl_xor(pB, off);
                pC += __shfl_xor(pC, off);
                pD += __shfl_xor(pD, off);
            }
            float eA = exp2f(pA), eB = exp2f(pB), eC = exp2f(pC), eD = exp2f(pD);
            l += (eA + eB) + (eC + eD);
            float2 vA0 = up2(A.z), vA1 = up2(A.w);
            float2 vB0 = up2(B.z), vB1 = up2(B.w);
            float2 vC0 = up2(Cv.z), vC1 = up2(Cv.w);
            float2 vD0 = up2(D.z), vD1 = up2(D.w);
            a0 = fmaf(eA, vA0.x, fmaf(eB, vB0.x, fmaf(eC, vC0.x, fmaf(eD, vD0.x, a0))));
            a1 = fmaf(eA, vA0.y, fmaf(eB, vB0.y, fmaf(eC, vC0.y, fmaf(eD, vD0.y, a1))));
            a2 = fmaf(eA, vA1.x, fmaf(eB, vB1.x, fmaf(eC, vC1.x, fmaf(eD, vD1.x, a2))));
            a3 = fmaf(eA, vA1.y, fmaf(eB, vB1.y, fmaf(eC, vC1.y, fmaf(eD, vD1.y, a3))));
        }
        if (ei + 1 < s1) {
            int iA = ldi<UNI>(ssrc, ei), iB = ldi<UNI>(ssrc, ei + 1);
            ei += 2;
            uint4 A = *(const uint4*)(F + (size_t)iA * Ms + kvoff);
            uint4 B = *(const uint4*)(F + (size_t)iB * Ms + kvoff);
            float pA = dot4(qa, qb, A.x, A.y);
            float pB = dot4(qa, qb, B.x, B.y);
#pragma unroll
            for (int off = C / 8; off > 0; off >>= 1) {
                pA += __shfl_xor(pA, off);
                pB += __shfl_xor(pB, off);
            }
            float eA = exp2f(pA), eB = exp2f(pB);
            l += eA + eB;
            float2 vA0 = up2(A.z), vA1 = up2(A.w);
            float2 vB0 = up2(B.z), vB1 = up2(B.w);
            a0 = fmaf(eA, vA0.x, fmaf(eB, vB0.x, a0));
            a1 = fmaf(eA, vA0.y, fmaf(eB, vB0.y, a1));
            a2 = fmaf(eA, vA1.x, fmaf(eB, vB1.x, a2));
            a3 = fmaf(eA, vA1.y, fmaf(eB, vB1.y, a3));
        }
        if (ei < s1) {
            int iA = ldi<UNI>(ssrc, ei);
            uint4 A = *(const uint4*)(F + (size_t)iA * Ms + kvoff);
            float pA = dot4(qa, qb, A.x, A.y);
#pragma unroll
            for (int off = C / 8; off > 0; off >>= 1) pA += __shfl_xor(pA, off);
            float eA = exp2f(pA);
            l += eA;
            float2 vA0 = up2(A.z), vA1 = up2(A.w);
            a0 = fmaf(eA, vA0.x, a0);
            a1 = fmaf(eA, vA0.y, a1);
            a2 = fmaf(eA, vA1.x, a2);
            a3 = fmaf(eA, vA1.y, a3);
        }
    }

    float inv = 1.f / (l + 1e-16f);
    float r0 = a0 * inv, r1 = a1 * inv, r2 = a2 * inv, r3 = a3 * inv;

    const int col = (h0 + head) * C + c4;
    if constexpr (YBF) {
        uint2* Hp = (uint2*)((unsigned short*)Hv + (size_t)n * ostride + col);
        uint2 hv = *Hp;
        float2 hx = up2(hv.x), hy = up2(hv.y);
        float o0 = hx.x + r0, o1 = hx.y + r1, o2 = hy.x + r2, o3 = hy.y + r3;
        if (RELU) {
            o0 = fmaxf(o0, 0.f); o1 = fmaxf(o1, 0.f);
            o2 = fmaxf(o2, 0.f); o3 = fmaxf(o3, 0.f);
        }
        uint2 pv;
        pv.x = (unsigned)f2b(o0) | ((unsigned)f2b(o1) << 16);
        pv.y = (unsigned)f2b(o2) | ((unsigned)f2b(o3) << 16);
        *Hp = pv;
    } else {
        float4* Hp = (float4*)((float*)Hv + (size_t)n * ostride + col);
        float4 h = *Hp;
        h.x += r0; h.y += r1; h.z += r2; h.w += r3;
        if (RELU) {
            h.x = fmaxf(h.x, 0.f); h.y = fmaxf(h.y, 0.f);
            h.z = fmaxf(h.z, 0.f); h.w = fmaxf(h.w, 0.f);
        }
        *Hp = h;
    }
}

static inline void launch_attn_L1(int NH, int h0, const unsigned short* F,
                                  const unsigned char* KV8, void* H, int ostride,
                                  const int* rowptr, const int* ssrc, hipStream_t stream) {
    switch (NH) {
        case 1: attn3<32, 1, true, true, 1><<<3125, 256, 0, stream>>>(F, KV8, rowptr, ssrc, H, h0, ostride); break;
        case 2: attn3<32, 2, true, true, 1><<<6250, 256, 0, stream>>>(F, KV8, rowptr, ssrc, H, h0, ostride); break;
        case 3: attn3<32, 3, true, true, 1><<<12500, 256, 0, stream>>>(F, KV8, rowptr, ssrc, H, h0, ostride); break;
        case 4: attn3<32, 4, true, true, 1><<<12500, 256, 0, stream>>>(F, KV8, rowptr, ssrc, H, h0, ostride); break;
        default: attn3<32, 7, true, true, 1><<<25000, 256, 0, stream>>>(F, KV8, rowptr, ssrc, H, h0, ostride); break;
    }
}

static inline void launch_attn_L2(int NH, int h0, const unsigned short* F,
                                  const unsigned char* K8, void* H, int ostride,
                                  const int* rowptr, const int* ssrc, hipStream_t stream) {
    switch (NH) {
        case 1: attn3<32, 1, true, true, 2><<<3125, 256, 0, stream>>>(F, K8, rowptr, ssrc, H, h0, ostride); break;
        case 2: attn3<32, 2, true, true, 2><<<6250, 256, 0, stream>>>(F, K8, rowptr, ssrc, H, h0, ostride); break;
        case 3: attn3<32, 3, true, true, 2><<<12500, 256, 0, stream>>>(F, K8, rowptr, ssrc, H, h0, ostride); break;
        default: attn3<32, 4, true, true, 2><<<12500, 256, 0, stream>>>(F, K8, rowptr, ssrc, H, h0, ostride); break;
    }
}

// ---------------- launch ----------------

extern "C" void kernel_launch(void* const* d_in, const int* in_sizes, int n_in,
                              void* d_out, int out_size, void* d_ws, size_t ws_size,
                              hipStream_t stream) {
    const float* x = (const float*)d_in[0];
    const int* ei = (const int*)d_in[1];
    const int* srcp = ei;
    const int* dstp = ei + N_EDGES;

    const float* W[12];
    const float* B[12];
    for (int i = 0; i < 12; ++i) {
        W[i] = (const float*)d_in[2 + 2 * i];
        B[i] = (const float*)d_in[3 + 2 * i];
    }
    float* out = (float*)d_out;

    // ---- workspace layout ----
    char* p = (char*)d_ws;
    size_t off = 0;
    unsigned short* wt  = (unsigned short*)(p + off); off += 240000;
    float* biasF        = (float*)(p + off);          off += 4096;
    int* rowptr = (int*)(p + off); off += sizeof(int) * (N_NODES + 1);
    int* deg    = (int*)(p + off); off += sizeof(int) * N_NODES;
    int* cursor = (int*)(p + off); off += sizeof(int) * N_NODES;
    int* partials = (int*)(p + off); off += sizeof(int) * 128;
    int* ssrc   = (int*)(p + off); off += sizeof(int) * N_EDGES;
    off = (off + 255) & ~(size_t)255;
    unsigned short* h1  = (unsigned short*)(p + off); off += (size_t)224 * N_NODES * 2;
    unsigned short* h2  = (unsigned short*)(p + off); off += (size_t)128 * N_NODES * 2;
    unsigned short* xb1 = (unsigned short*)(p + off); off += (size_t)64 * N_NODES * 2;
    unsigned short* tail = (unsigned short*)(p + off);

    if (ws_size < off + 6500000) {  // min config; telemetry if short
        fill_kernel<<<(out_size + 255) / 256, 256, 0, stream>>>(out, out_size, (float)(ws_size >> 20));
        return;
    }
    size_t tail_bytes = ws_size - off;
    const size_t F1PASS = (size_t)3 * 32 * N_NODES * 2;  // 19.2 MB budget per C=32 head
        // actual use/head: L1 (q bf16 + kv8 fp8) = 12.8 MB; L2 (q|v bf16 + k8) = 16 MB

    // head partitions per available F space
    int nh1[7], np1 = 0;
    int nh2[4], np2 = 0;
    unsigned short *F1w, *F2w;
    if (tail_bytes >= 7 * F1PASS) {          // 134.4 MB budget: single-pass both layers
        nh1[np1++] = 7;
        nh2[np2++] = 4;
        F1w = F2w = tail;
    } else if (tail_bytes >= 4 * F1PASS) {
        nh1[np1++] = 4; nh1[np1++] = 3;
        nh2[np2++] = 4;
        F1w = F2w = tail;
    } else if (tail_bytes >= 2 * F1PASS) {
        nh1[np1++] = 2; nh1[np1++] = 2; nh1[np1++] = 2; nh1[np1++] = 1;
        nh2[np2++] = 2; nh2[np2++] = 2;
        F1w = F2w = tail;
    } else {
        for (int i = 0; i < 7; ++i) nh1[np1++] = 1;
        for (int i = 0; i < 4; ++i) nh2[np2++] = 1;
        F1w = h2;   // h2 dead during layer 1 (12.8 MB <= 25.6 MB)
        F2w = xb1;  // xb1 dead during layer 2 (16 MB: 12.8 + spill into tail >= 6.5)
    }
    // layer3: h1 dead. F3 = q|v bf16 (25.6 MB) + K3 fp8 (6.4 MB) = 32 <= 44.8 MB
    unsigned short* F3 = h1;
    unsigned char* K3w = (unsigned char*)(h1 + (size_t)128 * N_NODES);

    hipMemsetAsync(deg, 0, sizeof(int) * 2 * N_NODES, stream);
    hist_kernel<<<(N_EDGES + 255) / 256, 256, 0, stream>>>(dstp, deg);
    scan_part<<<SCAN_BLOCKS, 1024, 0, stream>>>(deg, rowptr, partials);
    scan_tail<<<1, 128, 0, stream>>>(partials, rowptr);
    scan_add<<<SCAN_BLOCKS, 1024, 0, stream>>>(rowptr, partials);
    scatter_kernel<<<(N_EDGES + 255) / 256, 256, 0, stream>>>(srcp, dstp, rowptr, cursor, ssrc);

    convert_kernel<<<(N_NODES * 64 / 4 + 255) / 256, 256, 0, stream>>>(x, xb1, N_NODES * 64 / 4);

    // ---- Layer 1: K=64, H=7, C=32, HC=224, WT mode 1 [q|kv-int|s], fp8 kv ----
    build_wt<<<(4 * 224 * 64 + 255) / 256, 256, 0, stream>>>(
        W[0], W[1], W[2], W[3], B[0], B[1], B[2], B[3], wt, biasF, 64, 224, 32, 1);
    launch_gemm<64, 1>(xb1, wt + (size_t)3 * 224 * 64, biasF + 3 * 224, h1,
                       224, 224, /*split*/224, /*rq*/0, /*rkv*/0, stream);
    {
        int h0 = 0;
        for (int pass = 0; pass < np1; ++pass) {
            int NH = nh1[pass];
            int nc = NH * 32;
            unsigned char* K1w = (unsigned char*)F1w + (size_t)2 * nc * N_NODES;  // after q
            launch_gemm<64, 1>(xb1, wt, biasF, F1w, nc, nc,
                               /*split*/nc, /*rq*/h0 * 32, /*rkv*/0, stream);
            launch_gemm<64, 2>(xb1, wt, biasF, K1w, 2 * nc, 2 * nc,
                               /*split*/2 * nc, /*rq*/224 + 2 * h0 * 32, /*rkv*/0, stream);
            launch_attn_L1(NH, h0, F1w, K1w, h1, 224, rowptr, ssrc, stream);
            h0 += NH;
        }
    }

    // ---- Layer 2: K=224, H=4, C=32, HC=128, WT mode 0 [q|v|k|s], fp8 k only ----
    build_wt<<<(4 * 128 * 224 + 255) / 256, 256, 0, stream>>>(
        W[4], W[5], W[6], W[7], B[4], B[5], B[6], B[7], wt, biasF, 224, 128, 32, 0);
    launch_gemm<224, 1>(h1, wt + (size_t)3 * 128 * 224, biasF + 3 * 128, h2,
                        128, 128, /*split*/128, /*rq*/0, /*rkv*/0, stream);
    {
        int h0 = 0;
        for (int pass = 0; pass < np2; ++pass) {
            int NH = nh2[pass];
            int nc = NH * 32;
            unsigned char* K2w = (unsigned char*)F2w + (size_t)4 * nc * N_NODES;  // after q|v
            launch_gemm<224, 1>(h1, wt, biasF, F2w, 2 * nc, 2 * nc,
                                /*split*/nc, /*rq*/h0 * 32, /*rkv*/128 + h0 * 32, stream);
            launch_gemm<224, 2>(h1, wt, biasF, K2w, nc, nc,
                                /*split*/nc, /*rq*/2 * 128 + h0 * 32, /*rkv*/0, stream);
            launch_attn_L2(NH, h0, F2w, K2w, h2, 128, rowptr, ssrc, stream);
            h0 += NH;
        }
    }

    // ---- Layer 3: K=128, H=1, C=64, HC=64, WT mode 0 [q|v|k|s], fp8 k (r17) ----
    build_wt<<<(4 * 64 * 128 + 255) / 256, 256, 0, stream>>>(
        W[8], W[9], W[10], W[11], B[8], B[9], B[10], B[11], wt, biasF, 128, 64, 64, 0);
    // q|v bf16: WT rows 0..128 (identity map)
    launch_gemm<128, 1>(h2, wt, biasF, F3, 128, 128,
                        /*split*/128, /*rq*/0, /*rkv*/0, stream);
    // k fp8: WT rows 128..192
    launch_gemm<128, 2>(h2, wt, biasF, K3w, 64, 64,
                        /*split*/64, /*rq*/128, /*rkv*/0, stream);
    // skip (s): WT rows 192..256, f32 out
    launch_gemm<128, 0>(h2, wt, biasF, out, 64, 64,
                        /*split*/64, /*rq*/192, /*rkv*/0, stream);
    attn3<64, 1, false, false, 2><<<6250, 256, 0, stream>>>(F3, K3w, rowptr, ssrc, out, 0, 64);
}

// Round 10
// 620.439 us; speedup vs baseline: 1.0111x; 1.0111x over previous
//
#include <hip/hip_runtime.h>
#include <hip/hip_bf16.h>
#include <hip/hip_fp8.h>
#include <math.h>

#define N_NODES 100000
#define N_EDGES 800000
#define SCAN_BLOCKS 98  // ceil(100000/1024)

typedef __attribute__((ext_vector_type(8))) short short8;
typedef __attribute__((ext_vector_type(4))) float f32x4;
typedef __attribute__((ext_vector_type(2))) float f32x2;

__device__ __forceinline__ unsigned short f2b(float f) {
    __hip_bfloat16 h = __float2bfloat16(f);
    return *reinterpret_cast<unsigned short*>(&h);
}
__device__ __forceinline__ float2 up2(unsigned u) {
    unsigned lo = u << 16;
    unsigned hi = u & 0xffff0000u;
    float2 r;
    __builtin_memcpy(&r.x, &lo, 4);
    __builtin_memcpy(&r.y, &hi, 4);
    return r;
}
// fp32 -> fp8 e4m3 (RNE, saturating)
__device__ __forceinline__ unsigned char f2fp8(float f) {
#if __has_builtin(__builtin_amdgcn_cvt_pk_fp8_f32)
    unsigned u = __builtin_amdgcn_cvt_pk_fp8_f32(f, f, 0u, false);
    return (unsigned char)(u & 0xffu);
#else
    __hip_fp8_e4m3 h(f);
    return (unsigned char)h.__x;
#endif
}
// 4-ch dot: fp8-e4m3-packed k (4 bytes) against pre-scaled q
__device__ __forceinline__ float dotk(float2 qa, float2 qb, unsigned k4) {
#if __has_builtin(__builtin_amdgcn_cvt_pk_f32_fp8)
    f32x2 lo = __builtin_amdgcn_cvt_pk_f32_fp8(k4, false);
    f32x2 hi = __builtin_amdgcn_cvt_pk_f32_fp8(k4, true);
    float p = lo[0] * qa.x;
    p = fmaf(lo[1], qa.y, p);
    p = fmaf(hi[0], qb.x, p);
    p = fmaf(hi[1], qb.y, p);
    return p;
#else
    __hip_fp8_e4m3 a, b, c, d;
    a.__x = (unsigned char)k4;
    b.__x = (unsigned char)(k4 >> 8);
    c.__x = (unsigned char)(k4 >> 16);
    d.__x = (unsigned char)(k4 >> 24);
    float p = (float)a * qa.x;
    p = fmaf((float)b, qa.y, p);
    p = fmaf((float)c, qb.x, p);
    p = fmaf((float)d, qb.y, p);
    return p;
#endif
}
// fp8x4 -> 4 floats (v dequant)
__device__ __forceinline__ f32x4 up4f8(unsigned v) {
    f32x4 r;
#if __has_builtin(__builtin_amdgcn_cvt_pk_f32_fp8)
    f32x2 lo = __builtin_amdgcn_cvt_pk_f32_fp8(v, false);
    f32x2 hi = __builtin_amdgcn_cvt_pk_f32_fp8(v, true);
    r[0] = lo[0]; r[1] = lo[1]; r[2] = hi[0]; r[3] = hi[1];
#else
    __hip_fp8_e4m3 a, b, c, d;
    a.__x = (unsigned char)v;
    b.__x = (unsigned char)(v >> 8);
    c.__x = (unsigned char)(v >> 16);
    d.__x = (unsigned char)(v >> 24);
    r[0] = (float)a; r[1] = (float)b; r[2] = (float)c; r[3] = (float)d;
#endif
    return r;
}
// 4-ch bf16 dot against pre-scaled q (layer-3 interleaved path)
__device__ __forceinline__ float dot4(float2 qa, float2 qb, unsigned k0, unsigned k1) {
    float2 x = up2(k0), y = up2(k1);
    float p = x.x * qa.x;
    p = fmaf(x.y, qa.y, p);
    p = fmaf(y.x, qb.x, p);
    p = fmaf(y.y, qb.y, p);
    return p;
}
// edge-index load; UNI: whole wave owns one node -> index is wave-uniform,
// force it scalar so gather addressing moves to the SALU pipe (r16).
template <bool UNI>
__device__ __forceinline__ int ldi(const int* __restrict__ p, int e) {
    int v = p[e];
    if constexpr (UNI) v = __builtin_amdgcn_readfirstlane(v);
    return v;
}

// ---------------- CSR build (dst-sorted adjacency) ----------------

__global__ void hist_kernel(const int* __restrict__ dst, int* __restrict__ deg) {
    int e = blockIdx.x * blockDim.x + threadIdx.x;
    if (e < N_EDGES) atomicAdd(&deg[dst[e]], 1);
}

__global__ __launch_bounds__(1024) void scan_part(const int* __restrict__ deg,
                                                  int* __restrict__ rowptr,
                                                  int* __restrict__ partials) {
    __shared__ int buf[1024];
    const int t = threadIdx.x;
    const int i = blockIdx.x * 1024 + t;
    int x = (i < N_NODES) ? deg[i] : 0;
    buf[t] = x;
    __syncthreads();
    for (int off = 1; off < 1024; off <<= 1) {
        int y = (t >= off) ? buf[t - off] : 0;
        __syncthreads();
        buf[t] += y;
        __syncthreads();
    }
    if (i < N_NODES) rowptr[i] = buf[t] - x;
    if (t == 1023) partials[blockIdx.x] = buf[t];
}

__global__ __launch_bounds__(128) void scan_tail(int* __restrict__ partials,
                                                 int* __restrict__ rowptr) {
    __shared__ int buf[128];
    const int t = threadIdx.x;
    int x = (t < SCAN_BLOCKS) ? partials[t] : 0;
    buf[t] = x;
    __syncthreads();
    for (int off = 1; off < 128; off <<= 1) {
        int y = (t >= off) ? buf[t - off] : 0;
        __syncthreads();
        buf[t] += y;
        __syncthreads();
    }
    if (t < SCAN_BLOCKS) partials[t] = buf[t] - x;
    if (t == 127) rowptr[N_NODES] = buf[127];
}

__global__ __launch_bounds__(1024) void scan_add(int* __restrict__ rowptr,
                                                 const int* __restrict__ partials) {
    const int i = blockIdx.x * 1024 + threadIdx.x;
    if (i < N_NODES) rowptr[i] += partials[blockIdx.x];
}

__global__ void scatter_kernel(const int* __restrict__ src, const int* __restrict__ dst,
                               const int* __restrict__ rowptr, int* __restrict__ cursor,
                               int* __restrict__ sorted_src) {
    int e = blockIdx.x * blockDim.x + threadIdx.x;
    if (e < N_EDGES) {
        int d = dst[e];
        int pos = atomicAdd(&cursor[d], 1);
        sorted_src[rowptr[d] + pos] = src[e];
    }
}

__global__ void fill_kernel(float* __restrict__ out, int n, float val) {
    int i = blockIdx.x * blockDim.x + threadIdx.x;
    if (i < n) out[i] = val;
}

// ---------------- helpers ----------------

__global__ void convert_kernel(const float* __restrict__ X, unsigned short* __restrict__ Y, int n4) {
    int i = blockIdx.x * blockDim.x + threadIdx.x;
    if (i < n4) {
        float4 f = ((const float4*)X)[i];
        ushort4 u;
        u.x = f2b(f.x); u.y = f2b(f.y); u.z = f2b(f.z); u.w = f2b(f.w);
        ((ushort4*)Y)[i] = u;
    }
}

// WT[4*HC][K] bf16. mode 0 (layer 2): row order [q | v | k | s].
// mode 1 (layers 1,3): [q | kv-interleaved | s] (per head 2C rows, groups of 8
// = {k[g*4..+3], v[g*4..+3]} so the gather reads one contiguous chunk per lane).
// biasF[4*HC] fp32 in the same row order.
__global__ void build_wt(const float* __restrict__ Wq, const float* __restrict__ Wk,
                         const float* __restrict__ Wv, const float* __restrict__ Wsk,
                         const float* __restrict__ bq, const float* __restrict__ bk,
                         const float* __restrict__ bv, const float* __restrict__ bsk,
                         unsigned short* __restrict__ WT, float* __restrict__ biasF,
                         int K, int HC, int C, int mode) {
    int total = 4 * HC * K;
    int idx = blockIdx.x * blockDim.x + threadIdx.x;
    if (idx >= total) return;
    int rowc = idx / K;
    int kk = idx - rowc * K;
    const float* W;
    const float* Bp;
    int cw;
    if (mode == 0) {
        if (rowc < HC)          { W = Wq;  Bp = bq;  cw = rowc; }
        else if (rowc < 2 * HC) { W = Wv;  Bp = bv;  cw = rowc - HC; }
        else if (rowc < 3 * HC) { W = Wk;  Bp = bk;  cw = rowc - 2 * HC; }
        else                    { W = Wsk; Bp = bsk; cw = rowc - 3 * HC; }
    } else {
        if (rowc < HC) {
            W = Wq; Bp = bq; cw = rowc;
        } else if (rowc < 3 * HC) {
            int u = rowc - HC;
            int h = u / (2 * C);
            int rr = u - h * 2 * C;
            int grp = rr >> 3, w = rr & 7;
            if (w < 4) { W = Wk; Bp = bk; cw = h * C + grp * 4 + w; }
            else       { W = Wv; Bp = bv; cw = h * C + grp * 4 + w - 4; }
        } else {
            W = Wsk; Bp = bsk; cw = rowc - 3 * HC;
        }
    }
    WT[idx] = f2b(W[(size_t)kk * HC + cw]);
    if (kk == 0) biasF[rowc] = Bp[cw];
}

// ---------------- MFMA bf16 GEMM ----------------
// r7: X-refetch across col-tiles is L3-absorbed — never trade occupancy for
// fetch. r9: union-LDS epilogue. r10: 2-range col->WT-row map (split/rq/rkv).
// r11: YMODE 2 fp8-e4m3 epilogue. r13: fp8 kv only in layer 1.
// r14: XCD-pinned X-stationary block remap (+8 us measured).
// r18: L3 stays 2-pass bf16 (r9's 3-pass k-fp8 split regressed: extra GEMM
// pass costs more than the attn byte saving — same lesson as r3).
// YMODE: 0 = f32 out (ostride in floats), 1 = bf16 (shorts), 2 = fp8 (bytes).

template <int K, int YMODE>
__global__ __launch_bounds__(256) void mfma_gemm(
    const unsigned short* __restrict__ Xb, const unsigned short* __restrict__ WT,
    const float* __restrict__ biasF, void* __restrict__ Y,
    int ncols, int ostride, int split, int rq, int rkv) {
    constexpr int STR = 40;
    constexpr int ESTR = 136;  // bf16 epilogue row stride (shorts)
    __shared__ __align__(16) char smem[128 * ESTR * 2];  // 34816 B union
    unsigned short* Xs = (unsigned short*)smem;                  // 128*40 shorts
    unsigned short* Ws = (unsigned short*)(smem + 128 * STR * 2);
    const int t = threadIdx.x;
    const int wave = t >> 6, lane = t & 63, quad = lane >> 4, l16 = lane & 15;

    // XCD-pinned remap (r14)
    const int bid = blockIdx.x + blockIdx.y * gridDim.x;  // linear dispatch id
    const int nwg = gridDim.x * gridDim.y;
    const int nyt = gridDim.y;
    const int xcd = bid & 7;
    const int jj = bid >> 3;
    const int qq = nwg >> 3, rr = nwg & 7;
    const int base = xcd * qq + (xcd < rr ? xcd : rr);
    const int work = base + jj;
    const int xt = work / nyt;
    const int yt = work - xt * nyt;
    const int n0 = xt * 128, c0 = yt * 128;

    f32x4 acc[2][8];
#pragma unroll
    for (int i = 0; i < 2; ++i)
#pragma unroll
        for (int j = 0; j < 8; ++j)
#pragma unroll
            for (int r = 0; r < 4; ++r) acc[i][j][r] = 0.f;

    for (int k0 = 0; k0 < K; k0 += 32) {
#pragma unroll
        for (int i = 0; i < 2; ++i) {
            int idx = t + i * 256;
            int row = idx >> 2;
            int seg = (idx & 3) << 3;
            int gr = n0 + row;
            short8 xv;
#pragma unroll
            for (int z = 0; z < 8; ++z) xv[z] = 0;
            if (gr < N_NODES)
                xv = *(const short8*)(Xb + (size_t)gr * K + k0 + seg);
            *(short8*)(&Xs[row * STR + seg]) = xv;

            int c = c0 + row;
            short8 wv;
#pragma unroll
            for (int z = 0; z < 8; ++z) wv[z] = 0;
            if (c < ncols) {
                int wtrow = (c < split) ? (rq + c) : (rkv + (c - split));
                wv = *(const short8*)(WT + (size_t)wtrow * K + k0 + seg);
            }
            *(short8*)(&Ws[row * STR + seg]) = wv;
        }
        __syncthreads();

        short8 af0 = *(short8*)(&Xs[(wave * 32 + l16) * STR + quad * 8]);
        short8 af1 = *(short8*)(&Xs[(wave * 32 + 16 + l16) * STR + quad * 8]);
#pragma unroll
        for (int ct = 0; ct < 8; ++ct) {
            short8 bfr = *(short8*)(&Ws[(ct * 16 + l16) * STR + quad * 8]);
            acc[0][ct] = __builtin_amdgcn_mfma_f32_16x16x32_bf16(af0, bfr, acc[0][ct], 0, 0, 0);
            acc[1][ct] = __builtin_amdgcn_mfma_f32_16x16x32_bf16(af1, bfr, acc[1][ct], 0, 0, 0);
        }
        __syncthreads();  // also guards the epilogue's staging-LDS reuse
    }

    if constexpr (YMODE == 1) {
        unsigned short* Es = (unsigned short*)smem;  // 128 x ESTR, unioned
#pragma unroll
        for (int ct = 0; ct < 8; ++ct) {
            if (c0 + ct * 16 >= ncols) break;  // ncols % 32 == 0
            int col = c0 + ct * 16 + l16;
            int brow = (col < split) ? (rq + col) : (rkv + (col - split));
            float bv = biasF[brow];
#pragma unroll
            for (int rt = 0; rt < 2; ++rt)
#pragma unroll
                for (int r = 0; r < 4; ++r) {
                    int row = wave * 32 + rt * 16 + quad * 4 + r;
                    Es[row * ESTR + ct * 16 + l16] = f2b(acc[rt][ct][r] + bv);
                }
        }
        __syncthreads();
        const int erow = t >> 1;
        const int cb = (t & 1) * 8;
        const int gr = n0 + erow;
#pragma unroll
        for (int j = 0; j < 8; ++j) {
            int gc = c0 + j * 16 + cb;
            if (gr < N_NODES && gc < ncols)
                *(short8*)((unsigned short*)Y + (size_t)gr * ostride + gc) =
                    *(const short8*)(&Es[erow * ESTR + j * 16 + cb]);
        }
    } else if constexpr (YMODE == 2) {
        constexpr int EB = 144;  // byte stride, 16B-aligned
        unsigned char* Es = (unsigned char*)smem;  // 128 x EB bytes, unioned
#pragma unroll
        for (int ct = 0; ct < 8; ++ct) {
            if (c0 + ct * 16 >= ncols) break;  // ncols % 16 == 0
            int col = c0 + ct * 16 + l16;
            int brow = (col < split) ? (rq + col) : (rkv + (col - split));
            float bv = biasF[brow];
#pragma unroll
            for (int rt = 0; rt < 2; ++rt)
#pragma unroll
                for (int r = 0; r < 4; ++r) {
                    int row = wave * 32 + rt * 16 + quad * 4 + r;
                    Es[row * EB + ct * 16 + l16] = f2fp8(acc[rt][ct][r] + bv);
                }
        }
        __syncthreads();
        const int erow = t >> 1;
        const int q8 = (t & 1) * 64;
        const int gr = n0 + erow;
#pragma unroll
        for (int j = 0; j < 4; ++j) {
            int gc = c0 + q8 + j * 16;
            if (gr < N_NODES && gc < ncols)
                *(uint4*)((unsigned char*)Y + (size_t)gr * ostride + gc) =
                    *(const uint4*)(&Es[erow * EB + q8 + j * 16]);
        }
    } else {
#pragma unroll
        for (int ct = 0; ct < 8; ++ct) {
            int col = c0 + ct * 16 + l16;
            if (col >= ncols) continue;
            int brow = (col < split) ? (rq + col) : (rkv + (col - split));
            float bv = biasF[brow];
#pragma unroll
            for (int rt = 0; rt < 2; ++rt) {
#pragma unroll
                for (int r = 0; r < 4; ++r) {
                    int row = n0 + wave * 32 + rt * 16 + quad * 4 + r;
                    if (row < N_NODES)
                        ((float*)Y)[(size_t)row * ostride + col] = acc[rt][ct][r] + bv;
                }
            }
        }
    }
}

template <int K, int YMODE>
static inline void launch_gemm(const unsigned short* Xb, const unsigned short* WT,
                               const float* biasF, void* Y, int ncols, int ostride,
                               int split, int rq, int rkv, hipStream_t s) {
    const int GX = (N_NODES + 127) / 128;
    int ny = (ncols + 127) / 128;
    mfma_gemm<K, YMODE><<<dim3(GX, ny), 256, 0, s>>>(
        Xb, WT, biasF, Y, ncols, ostride, split, rq, rkv);
}

// ---------------- attention v7r: per-layer kv precision, 4 ch/lane ----------
// KVM 0 (layer 3): F row [q | kv-int bf16 | ...], one 16B gather per lane.
// KVM 1 (layer 1): F row = q only (gC shorts); KV8 row = 2*gC bytes e4m3,
//   per head groups of 8 {k4|v4}: ONE uint2 (8B) gather per lane per edge.
// KVM 2 (layer 2): F row [q|v] bf16 (2*gC shorts); K8 row = gC bytes e4m3 k:
//   4B k + 8B v per lane per edge (v stays bf16 for accuracy).
// r16: when NPW==1 (NH=7 L1) the edge index is wave-uniform -> readfirstlane
// moves gather addressing to the SALU pipe (r6 counters: VALUBusy 67%).
// Logits tiny -> plain exp softmax is exact fp32. Dest holds skip; add (+ReLU).

template <int C, int NH, bool RELU, bool YBF, int KVM>
__global__ __launch_bounds__(256) void attn3(
    const unsigned short* __restrict__ F, const unsigned char* __restrict__ K8,
    const int* __restrict__ rowptr, const int* __restrict__ ssrc,
    void* __restrict__ Hv, int h0, int ostride) {
    constexpr int LPN = NH * C / 4;  // lanes per node
    constexpr int NPW = 64 / LPN;    // nodes per wave
    constexpr bool UNI = (NPW == 1); // wave-uniform edge indices
    constexpr int gC = NH * C;
    constexpr int Ms = (KVM == 1) ? gC : (KVM == 2) ? (2 * gC) : (3 * gC);
    constexpr int Mk = 2 * gC;       // KVM1 KV8 row stride (bytes)
    const int lane = threadIdx.x & 63;
    const int wave = (blockIdx.x * 256 + threadIdx.x) >> 6;
    const int slot = lane / LPN;
    const int cl = lane - slot * LPN;
    const int n = wave * NPW + slot;
    if (slot >= NPW || n >= N_NODES) return;  // no barriers below

    const int head = cl / (C / 4);
    const int c4 = (cl - head * (C / 4)) * 4;
    const int qoff = head * C + c4;
    const int voff = gC + qoff;                    // KVM2 v section (shorts)
    const int kv8off = 2 * (head * C + c4);        // KVM1 bytes {k4|v4}
    const int kvoff = gC + head * 2 * C + 2 * c4;  // KVM0 shorts interleaved
    const float SCALE2 = ((C == 64) ? 0.125f : 0.17677669529663687f) * 1.44269504f;

    uint2 qu = *(const uint2*)(F + (size_t)n * Ms + qoff);
    float2 qa = up2(qu.x), qb = up2(qu.y);
    qa.x *= SCALE2; qa.y *= SCALE2; qb.x *= SCALE2; qb.y *= SCALE2;
    int s0 = rowptr[n], s1 = rowptr[n + 1];
    if constexpr (UNI) {
        s0 = __builtin_amdgcn_readfirstlane(s0);
        s1 = __builtin_amdgcn_readfirstlane(s1);
    }

    float l = 0.f, a0 = 0.f, a1 = 0.f, a2 = 0.f, a3 = 0.f;
    int ei = s0;
    if constexpr (KVM == 1) {
        for (; ei + 3 < s1; ei += 4) {
            int iA = ldi<UNI>(ssrc, ei), iB = ldi<UNI>(ssrc, ei + 1);
            int iC = ldi<UNI>(ssrc, ei + 2), iD = ldi<UNI>(ssrc, ei + 3);
            uint2 A = *(const uint2*)(K8 + (size_t)iA * Mk + kv8off);
            uint2 B = *(const uint2*)(K8 + (size_t)iB * Mk + kv8off);
            uint2 Cu = *(const uint2*)(K8 + (size_t)iC * Mk + kv8off);
            uint2 D = *(const uint2*)(K8 + (size_t)iD * Mk + kv8off);
            float pA = dotk(qa, qb, A.x);
            float pB = dotk(qa, qb, B.x);
            float pC = dotk(qa, qb, Cu.x);
            float pD = dotk(qa, qb, D.x);
#pragma unroll
            for (int off = C / 8; off > 0; off >>= 1) {
                pA += __shfl_xor(pA, off);
                pB += __shfl_xor(pB, off);
                pC += __shfl_xor(pC, off);
                pD += __shfl_xor(pD, off);
            }
            float eA = exp2f(pA), eB = exp2f(pB), eC = exp2f(pC), eD = exp2f(pD);
            l += (eA + eB) + (eC + eD);
            f32x4 vA = up4f8(A.y), vB = up4f8(B.y), vC = up4f8(Cu.y), vD = up4f8(D.y);
            a0 = fmaf(eA, vA[0], fmaf(eB, vB[0], fmaf(eC, vC[0], fmaf(eD, vD[0], a0))));
            a1 = fmaf(eA, vA[1], fmaf(eB, vB[1], fmaf(eC, vC[1], fmaf(eD, vD[1], a1))));
            a2 = fmaf(eA, vA[2], fmaf(eB, vB[2], fmaf(eC, vC[2], fmaf(eD, vD[2], a2))));
            a3 = fmaf(eA, vA[3], fmaf(eB, vB[3], fmaf(eC, vC[3], fmaf(eD, vD[3], a3))));
        }
        if (ei + 1 < s1) {
            int iA = ldi<UNI>(ssrc, ei), iB = ldi<UNI>(ssrc, ei + 1);
            ei += 2;
            uint2 A = *(const uint2*)(K8 + (size_t)iA * Mk + kv8off);
            uint2 B = *(const uint2*)(K8 + (size_t)iB * Mk + kv8off);
            float pA = dotk(qa, qb, A.x);
            float pB = dotk(qa, qb, B.x);
#pragma unroll
            for (int off = C / 8; off > 0; off >>= 1) {
                pA += __shfl_xor(pA, off);
                pB += __shfl_xor(pB, off);
            }
            float eA = exp2f(pA), eB = exp2f(pB);
            l += eA + eB;
            f32x4 vA = up4f8(A.y), vB = up4f8(B.y);
            a0 = fmaf(eA, vA[0], fmaf(eB, vB[0], a0));
            a1 = fmaf(eA, vA[1], fmaf(eB, vB[1], a1));
            a2 = fmaf(eA, vA[2], fmaf(eB, vB[2], a2));
            a3 = fmaf(eA, vA[3], fmaf(eB, vB[3], a3));
        }
        if (ei < s1) {
            int iA = ldi<UNI>(ssrc, ei);
            uint2 A = *(const uint2*)(K8 + (size_t)iA * Mk + kv8off);
            float pA = dotk(qa, qb, A.x);
#pragma unroll
            for (int off = C / 8; off > 0; off >>= 1) pA += __shfl_xor(pA, off);
            float eA = exp2f(pA);
            l += eA;
            f32x4 vA = up4f8(A.y);
            a0 = fmaf(eA, vA[0], a0);
            a1 = fmaf(eA, vA[1], a1);
            a2 = fmaf(eA, vA[2], a2);
            a3 = fmaf(eA, vA[3], a3);
        }
    } else if constexpr (KVM == 2) {
        for (; ei + 3 < s1; ei += 4) {
            int iA = ldi<UNI>(ssrc, ei), iB = ldi<UNI>(ssrc, ei + 1);
            int iC = ldi<UNI>(ssrc, ei + 2), iD = ldi<UNI>(ssrc, ei + 3);
            unsigned kA = *(const unsigned*)(K8 + (size_t)iA * gC + qoff);
            unsigned kB = *(const unsigned*)(K8 + (size_t)iB * gC + qoff);
            unsigned kC = *(const unsigned*)(K8 + (size_t)iC * gC + qoff);
            unsigned kD = *(const unsigned*)(K8 + (size_t)iD * gC + qoff);
            uint2 vAu = *(const uint2*)(F + (size_t)iA * Ms + voff);
            uint2 vBu = *(const uint2*)(F + (size_t)iB * Ms + voff);
            uint2 vCu = *(const uint2*)(F + (size_t)iC * Ms + voff);
            uint2 vDu = *(const uint2*)(F + (size_t)iD * Ms + voff);
            float pA = dotk(qa, qb, kA);
            float pB = dotk(qa, qb, kB);
            float pC = dotk(qa, qb, kC);
            float pD = dotk(qa, qb, kD);
#pragma unroll
            for (int off = C / 8; off > 0; off >>= 1) {
                pA += __shfl_xor(pA, off);
                pB += __shfl_xor(pB, off);
                pC += __shfl_xor(pC, off);
                pD += __shfl_xor(pD, off);
            }
            float eA = exp2f(pA), eB = exp2f(pB), eC = exp2f(pC), eD = exp2f(pD);
            l += (eA + eB) + (eC + eD);
            float2 vA0 = up2(vAu.x), vA1 = up2(vAu.y);
            float2 vB0 = up2(vBu.x), vB1 = up2(vBu.y);
            float2 vC0 = up2(vCu.x), vC1 = up2(vCu.y);
            float2 vD0 = up2(vDu.x), vD1 = up2(vDu.y);
            a0 = fmaf(eA, vA0.x, fmaf(eB, vB0.x, fmaf(eC, vC0.x, fmaf(eD, vD0.x, a0))));
            a1 = fmaf(eA, vA0.y, fmaf(eB, vB0.y, fmaf(eC, vC0.y, fmaf(eD, vD0.y, a1))));
            a2 = fmaf(eA, vA1.x, fmaf(eB, vB1.x, fmaf(eC, vC1.x, fmaf(eD, vD1.x, a2))));
            a3 = fmaf(eA, vA1.y, fmaf(eB, vB1.y, fmaf(eC, vC1.y, fmaf(eD, vD1.y, a3))));
        }
        if (ei + 1 < s1) {
            int iA = ldi<UNI>(ssrc, ei), iB = ldi<UNI>(ssrc, ei + 1);
            ei += 2;
            unsigned kA = *(const unsigned*)(K8 + (size_t)iA * gC + qoff);
            unsigned kB = *(const unsigned*)(K8 + (size_t)iB * gC + qoff);
            uint2 vAu = *(const uint2*)(F + (size_t)iA * Ms + voff);
            uint2 vBu = *(const uint2*)(F + (size_t)iB * Ms + voff);
            float pA = dotk(qa, qb, kA);
            float pB = dotk(qa, qb, kB);
#pragma unroll
            for (int off = C / 8; off > 0; off >>= 1) {
                pA += __shfl_xor(pA, off);
                pB += __shfl_xor(pB, off);
            }
            float eA = exp2f(pA), eB = exp2f(pB);
            l += eA + eB;
            float2 vA0 = up2(vAu.x), vA1 = up2(vAu.y);
            float2 vB0 = up2(vBu.x), vB1 = up2(vBu.y);
            a0 = fmaf(eA, vA0.x, fmaf(eB, vB0.x, a0));
            a1 = fmaf(eA, vA0.y, fmaf(eB, vB0.y, a1));
            a2 = fmaf(eA, vA1.x, fmaf(eB, vB1.x, a2));
            a3 = fmaf(eA, vA1.y, fmaf(eB, vB1.y, a3));
        }
        if (ei < s1) {
            int iA = ldi<UNI>(ssrc, ei);
            unsigned kA = *(const unsigned*)(K8 + (size_t)iA * gC + qoff);
            uint2 vAu = *(const uint2*)(F + (size_t)iA * Ms + voff);
            float pA = dotk(qa, qb, kA);
#pragma unroll
            for (int off = C / 8; off > 0; off >>= 1) pA += __shfl_xor(pA, off);
            float eA = exp2f(pA);
            l += eA;
            float2 vA0 = up2(vAu.x), vA1 = up2(vAu.y);
            a0 = fmaf(eA, vA0.x, a0);
            a1 = fmaf(eA, vA0.y, a1);
            a2 = fmaf(eA, vA1.x, a2);
            a3 = fmaf(eA, vA1.y, a3);
        }
    } else {
        for (; ei + 3 < s1; ei += 4) {
            int iA = ldi<UNI>(ssrc, ei), iB = ldi<UNI>(ssrc, ei + 1);
            int iC = ldi<UNI>(ssrc, ei + 2), iD = ldi<UNI>(ssrc, ei + 3);
            uint4 A = *(const uint4*)(F + (size_t)iA * Ms + kvoff);
            uint4 B = *(const uint4*)(F + (size_t)iB * Ms + kvoff);
            uint4 Cv = *(const uint4*)(F + (size_t)iC * Ms + kvoff);
            uint4 D = *(const uint4*)(F + (size_t)iD * Ms + kvoff);
            float pA = dot4(qa, qb, A.x, A.y);
            float pB = dot4(qa, qb, B.x, B.y);
            float pC = dot4(qa, qb, Cv.x, Cv.y);
            float pD = dot4(qa, qb, D.x, D.y);
#pragma unroll
            for (int off = C / 8; off > 0; off >>= 1) {
                pA += __shfl_xor(pA, off);
                pB += __shfl_xor(pB, off);
                pC += __shfl_xor(pC, off);
                pD += __shfl_xor(pD, off);
            }
            float eA = exp2f(pA), eB = exp2f(pB), eC = exp2f(pC), eD = exp2f(pD);
            l += (eA + eB) + (eC + eD);
            float2 vA0 = up2(A.z), vA1 = up2(A.w);
            float2 vB0 = up2(B.z), vB1 = up2(B.w);
            float2 vC0 = up2(Cv.z), vC1 = up2(Cv.w);
            float2 vD0 = up2(D.z), vD1 = up2(D.w);
            a0 = fmaf(eA, vA0.x, fmaf(eB, vB0.x, fmaf(eC, vC0.x, fmaf(eD, vD0.x, a0))));
            a1 = fmaf(eA, vA0.y, fmaf(eB, vB0.y, fmaf(eC, vC0.y, fmaf(eD, vD0.y, a1))));
            a2 = fmaf(eA, vA1.x, fmaf(eB, vB1.x, fmaf(eC, vC1.x, fmaf(eD, vD1.x, a2))));
            a3 = fmaf(eA, vA1.y, fmaf(eB, vB1.y, fmaf(eC, vC1.y, fmaf(eD, vD1.y, a3))));
        }
        if (ei + 1 < s1) {
            int iA = ldi<UNI>(ssrc, ei), iB = ldi<UNI>(ssrc, ei + 1);
            ei += 2;
            uint4 A = *(const uint4*)(F + (size_t)iA * Ms + kvoff);
            uint4 B = *(const uint4*)(F + (size_t)iB * Ms + kvoff);
            float pA = dot4(qa, qb, A.x, A.y);
            float pB = dot4(qa, qb, B.x, B.y);
#pragma unroll
            for (int off = C / 8; off > 0; off >>= 1) {
                pA += __shfl_xor(pA, off);
                pB += __shfl_xor(pB, off);
            }
            float eA = exp2f(pA), eB = exp2f(pB);
            l += eA + eB;
            float2 vA0 = up2(A.z), vA1 = up2(A.w);
            float2 vB0 = up2(B.z), vB1 = up2(B.w);
            a0 = fmaf(eA, vA0.x, fmaf(eB, vB0.x, a0));
            a1 = fmaf(eA, vA0.y, fmaf(eB, vB0.y, a1));
            a2 = fmaf(eA, vA1.x, fmaf(eB, vB1.x, a2));
            a3 = fmaf(eA, vA1.y, fmaf(eB, vB1.y, a3));
        }
        if (ei < s1) {
            int iA = ldi<UNI>(ssrc, ei);
            uint4 A = *(const uint4*)(F + (size_t)iA * Ms + kvoff);
            float pA = dot4(qa, qb, A.x, A.y);
#pragma unroll
            for (int off = C / 8; off > 0; off >>= 1) pA += __shfl_xor(pA, off);
            float eA = exp2f(pA);
            l += eA;
            float2 vA0 = up2(A.z), vA1 = up2(A.w);
            a0 = fmaf(eA, vA0.x, a0);
            a1 = fmaf(eA, vA0.y, a1);
            a2 = fmaf(eA, vA1.x, a2);
            a3 = fmaf(eA, vA1.y, a3);
        }
    }

    float inv = 1.f / (l + 1e-16f);
    float r0 = a0 * inv, r1 = a1 * inv, r2 = a2 * inv, r3 = a3 * inv;

    const int col = (h0 + head) * C + c4;
    if constexpr (YBF) {
        uint2* Hp = (uint2*)((unsigned short*)Hv + (size_t)n * ostride + col);
        uint2 hv = *Hp;
        float2 hx = up2(hv.x), hy = up2(hv.y);
        float o0 = hx.x + r0, o1 = hx.y + r1, o2 = hy.x + r2, o3 = hy.y + r3;
        if (RELU) {
            o0 = fmaxf(o0, 0.f); o1 = fmaxf(o1, 0.f);
            o2 = fmaxf(o2, 0.f); o3 = fmaxf(o3, 0.f);
        }
        uint2 pv;
        pv.x = (unsigned)f2b(o0) | ((unsigned)f2b(o1) << 16);
        pv.y = (unsigned)f2b(o2) | ((unsigned)f2b(o3) << 16);
        *Hp = pv;
    } else {
        float4* Hp = (float4*)((float*)Hv + (size_t)n * ostride + col);
        float4 h = *Hp;
        h.x += r0; h.y += r1; h.z += r2; h.w += r3;
        if (RELU) {
            h.x = fmaxf(h.x, 0.f); h.y = fmaxf(h.y, 0.f);
            h.z = fmaxf(h.z, 0.f); h.w = fmaxf(h.w, 0.f);
        }
        *Hp = h;
    }
}

static inline void launch_attn_L1(int NH, int h0, const unsigned short* F,
                                  const unsigned char* KV8, void* H, int ostride,
                                  const int* rowptr, const int* ssrc, hipStream_t stream) {
    switch (NH) {
        case 1: attn3<32, 1, true, true, 1><<<3125, 256, 0, stream>>>(F, KV8, rowptr, ssrc, H, h0, ostride); break;
        case 2: attn3<32, 2, true, true, 1><<<6250, 256, 0, stream>>>(F, KV8, rowptr, ssrc, H, h0, ostride); break;
        case 3: attn3<32, 3, true, true, 1><<<12500, 256, 0, stream>>>(F, KV8, rowptr, ssrc, H, h0, ostride); break;
        case 4: attn3<32, 4, true, true, 1><<<12500, 256, 0, stream>>>(F, KV8, rowptr, ssrc, H, h0, ostride); break;
        default: attn3<32, 7, true, true, 1><<<25000, 256, 0, stream>>>(F, KV8, rowptr, ssrc, H, h0, ostride); break;
    }
}

static inline void launch_attn_L2(int NH, int h0, const unsigned short* F,
                                  const unsigned char* K8, void* H, int ostride,
                                  const int* rowptr, const int* ssrc, hipStream_t stream) {
    switch (NH) {
        case 1: attn3<32, 1, true, true, 2><<<3125, 256, 0, stream>>>(F, K8, rowptr, ssrc, H, h0, ostride); break;
        case 2: attn3<32, 2, true, true, 2><<<6250, 256, 0, stream>>>(F, K8, rowptr, ssrc, H, h0, ostride); break;
        case 3: attn3<32, 3, true, true, 2><<<12500, 256, 0, stream>>>(F, K8, rowptr, ssrc, H, h0, ostride); break;
        default: attn3<32, 4, true, true, 2><<<12500, 256, 0, stream>>>(F, K8, rowptr, ssrc, H, h0, ostride); break;
    }
}

// ---------------- launch ----------------

extern "C" void kernel_launch(void* const* d_in, const int* in_sizes, int n_in,
                              void* d_out, int out_size, void* d_ws, size_t ws_size,
                              hipStream_t stream) {
    const float* x = (const float*)d_in[0];
    const int* ei = (const int*)d_in[1];
    const int* srcp = ei;
    const int* dstp = ei + N_EDGES;

    const float* W[12];
    const float* B[12];
    for (int i = 0; i < 12; ++i) {
        W[i] = (const float*)d_in[2 + 2 * i];
        B[i] = (const float*)d_in[3 + 2 * i];
    }
    float* out = (float*)d_out;

    // ---- workspace layout ----
    char* p = (char*)d_ws;
    size_t off = 0;
    unsigned short* wt  = (unsigned short*)(p + off); off += 240000;
    float* biasF        = (float*)(p + off);          off += 4096;
    int* rowptr = (int*)(p + off); off += sizeof(int) * (N_NODES + 1);
    int* deg    = (int*)(p + off); off += sizeof(int) * N_NODES;
    int* cursor = (int*)(p + off); off += sizeof(int) * N_NODES;
    int* partials = (int*)(p + off); off += sizeof(int) * 128;
    int* ssrc   = (int*)(p + off); off += sizeof(int) * N_EDGES;
    off = (off + 255) & ~(size_t)255;
    unsigned short* h1  = (unsigned short*)(p + off); off += (size_t)224 * N_NODES * 2;
    unsigned short* h2  = (unsigned short*)(p + off); off += (size_t)128 * N_NODES * 2;
    unsigned short* xb1 = (unsigned short*)(p + off); off += (size_t)64 * N_NODES * 2;
    unsigned short* tail = (unsigned short*)(p + off);

    if (ws_size < off + 6500000) {  // min config; telemetry if short
        fill_kernel<<<(out_size + 255) / 256, 256, 0, stream>>>(out, out_size, (float)(ws_size >> 20));
        return;
    }
    size_t tail_bytes = ws_size - off;
    const size_t F1PASS = (size_t)3 * 32 * N_NODES * 2;  // 19.2 MB budget per C=32 head
        // actual use/head: L1 (q bf16 + kv8 fp8) = 12.8 MB; L2 (q|v bf16 + k8) = 16 MB

    // head partitions per available F space
    int nh1[7], np1 = 0;
    int nh2[4], np2 = 0;
    unsigned short *F1w, *F2w;
    if (tail_bytes >= 7 * F1PASS) {          // 134.4 MB budget: single-pass both layers
        nh1[np1++] = 7;
        nh2[np2++] = 4;
        F1w = F2w = tail;
    } else if (tail_bytes >= 4 * F1PASS) {
        nh1[np1++] = 4; nh1[np1++] = 3;
        nh2[np2++] = 4;
        F1w = F2w = tail;
    } else if (tail_bytes >= 2 * F1PASS) {
        nh1[np1++] = 2; nh1[np1++] = 2; nh1[np1++] = 2; nh1[np1++] = 1;
        nh2[np2++] = 2; nh2[np2++] = 2;
        F1w = F2w = tail;
    } else {
        for (int i = 0; i < 7; ++i) nh1[np1++] = 1;
        for (int i = 0; i < 4; ++i) nh2[np2++] = 1;
        F1w = h2;   // h2 dead during layer 1 (12.8 MB <= 25.6 MB)
        F2w = xb1;  // xb1 dead during layer 2 (16 MB: 12.8 + spill into tail >= 6.5)
    }
    unsigned short* F3 = h1;  // layer3: h1 dead (38.4 <= 44.8 MB)

    hipMemsetAsync(deg, 0, sizeof(int) * 2 * N_NODES, stream);
    hist_kernel<<<(N_EDGES + 255) / 256, 256, 0, stream>>>(dstp, deg);
    scan_part<<<SCAN_BLOCKS, 1024, 0, stream>>>(deg, rowptr, partials);
    scan_tail<<<1, 128, 0, stream>>>(partials, rowptr);
    scan_add<<<SCAN_BLOCKS, 1024, 0, stream>>>(rowptr, partials);
    scatter_kernel<<<(N_EDGES + 255) / 256, 256, 0, stream>>>(srcp, dstp, rowptr, cursor, ssrc);

    convert_kernel<<<(N_NODES * 64 / 4 + 255) / 256, 256, 0, stream>>>(x, xb1, N_NODES * 64 / 4);

    // ---- Layer 1: K=64, H=7, C=32, HC=224, WT mode 1 [q|kv-int|s], fp8 kv ----
    build_wt<<<(4 * 224 * 64 + 255) / 256, 256, 0, stream>>>(
        W[0], W[1], W[2], W[3], B[0], B[1], B[2], B[3], wt, biasF, 64, 224, 32, 1);
    launch_gemm<64, 1>(xb1, wt + (size_t)3 * 224 * 64, biasF + 3 * 224, h1,
                       224, 224, /*split*/224, /*rq*/0, /*rkv*/0, stream);
    {
        int h0 = 0;
        for (int pass = 0; pass < np1; ++pass) {
            int NH = nh1[pass];
            int nc = NH * 32;
            unsigned char* K1w = (unsigned char*)F1w + (size_t)2 * nc * N_NODES;  // after q
            launch_gemm<64, 1>(xb1, wt, biasF, F1w, nc, nc,
                               /*split*/nc, /*rq*/h0 * 32, /*rkv*/0, stream);
            launch_gemm<64, 2>(xb1, wt, biasF, K1w, 2 * nc, 2 * nc,
                               /*split*/2 * nc, /*rq*/224 + 2 * h0 * 32, /*rkv*/0, stream);
            launch_attn_L1(NH, h0, F1w, K1w, h1, 224, rowptr, ssrc, stream);
            h0 += NH;
        }
    }

    // ---- Layer 2: K=224, H=4, C=32, HC=128, WT mode 0 [q|v|k|s], fp8 k only ----
    build_wt<<<(4 * 128 * 224 + 255) / 256, 256, 0, stream>>>(
        W[4], W[5], W[6], W[7], B[4], B[5], B[6], B[7], wt, biasF, 224, 128, 32, 0);
    launch_gemm<224, 1>(h1, wt + (size_t)3 * 128 * 224, biasF + 3 * 128, h2,
                        128, 128, /*split*/128, /*rq*/0, /*rkv*/0, stream);
    {
        int h0 = 0;
        for (int pass = 0; pass < np2; ++pass) {
            int NH = nh2[pass];
            int nc = NH * 32;
            unsigned char* K2w = (unsigned char*)F2w + (size_t)4 * nc * N_NODES;  // after q|v
            launch_gemm<224, 1>(h1, wt, biasF, F2w, 2 * nc, 2 * nc,
                                /*split*/nc, /*rq*/h0 * 32, /*rkv*/128 + h0 * 32, stream);
            launch_gemm<224, 2>(h1, wt, biasF, K2w, nc, nc,
                                /*split*/nc, /*rq*/2 * 128 + h0 * 32, /*rkv*/0, stream);
            launch_attn_L2(NH, h0, F2w, K2w, h2, 128, rowptr, ssrc, stream);
            h0 += NH;
        }
    }

    // ---- Layer 3: K=128, H=1, C=64, HC=64, WT mode 1 [q|kv-int|s] (bf16) ----
    build_wt<<<(4 * 64 * 128 + 255) / 256, 256, 0, stream>>>(
        W[8], W[9], W[10], W[11], B[8], B[9], B[10], B[11], wt, biasF, 128, 64, 64, 1);
    launch_gemm<128, 1>(h2, wt, biasF, F3, 192, 192,
                        /*split*/64, /*rq*/0, /*rkv*/64, stream);
    launch_gemm<128, 0>(h2, wt + (size_t)3 * 64 * 128, biasF + 3 * 64, out,
                        64, 64, /*split*/64, /*rq*/0, /*rkv*/0, stream);
    attn3<64, 1, false, false, 0><<<6250, 256, 0, stream>>>(F3, (const unsigned char*)nullptr,
                                                            rowptr, ssrc, out, 0, 64);
}